// Round 5
// baseline (343.482 us; speedup 1.0000x reference)
//
#include <hip/hip_runtime.h>
#include <math.h>

#define NQc 40000
#define Wc 200
#define Hc 200

typedef __attribute__((ext_vector_type(8))) short short8;
typedef __attribute__((ext_vector_type(4))) float f32x4;

__device__ __forceinline__ ushort f2b(float f) {
  unsigned u = __float_as_uint(f);
  u = (u + 0x7fffu + ((u >> 16) & 1u)) >> 16;
  return (ushort)u;
}

// ---------------------------------------------------------------------------
// prep: activations -> bf16 Aq = [query | query+query_pos] (NQ,512);
// weights -> bf16 transposed (N,K).
// ---------------------------------------------------------------------------
__global__ __launch_bounds__(256) void prep_all(
    const float* __restrict__ q, const float* __restrict__ qp,
    const float* __restrict__ Wv, const float* __restrict__ Wo,
    const float* __restrict__ Wso, const float* __restrict__ Waw,
    ushort* __restrict__ Aq, ushort* __restrict__ WvT, ushort* __restrict__ WoT,
    ushort* __restrict__ WsoT, ushort* __restrict__ WawT) {
  const int b = blockIdx.x;
  if (b < 10000) {
    const int idx = b * 256 + threadIdx.x;
    const int m = idx >> 6;
    const int c = (idx & 63) * 4;
    float4 a = *(const float4*)&q[(size_t)m * 256 + c];
    float4 p = *(const float4*)&qp[(size_t)m * 256 + c];
    ushort4 o1 = { f2b(a.x), f2b(a.y), f2b(a.z), f2b(a.w) };
    ushort4 o2 = { f2b(a.x + p.x), f2b(a.y + p.y), f2b(a.z + p.z), f2b(a.w + p.w) };
    *(ushort4*)&Aq[(size_t)m * 512 + c] = o1;
    *(ushort4*)&Aq[(size_t)m * 512 + 256 + c] = o2;
  } else {
    const int idx = (b - 10000) * 256 + threadIdx.x;
    if (idx < 65536) {
      int n = idx >> 8, k = idx & 255;
      WvT[idx] = f2b(Wv[k * 256 + n]);
    } else if (idx < 131072) {
      int i = idx - 65536;
      int n = i >> 8, k = i & 255;
      WoT[i] = f2b(Wo[k * 256 + n]);
    } else if (idx < 196608) {
      int i = idx - 131072;
      int n = i >> 9, k = i & 511;
      WsoT[i] = f2b(Wso[k * 128 + n]);
    } else {
      int i = idx - 196608;
      int n = i >> 9, k = i & 511;
      WawT[i] = f2b(Waw[k * 64 + n]);
    }
  }
}

// ---------------------------------------------------------------------------
// BM=64 GEMM structure: 256 threads = 4 waves; wave w owns rows [w*16,w*16+16);
// acc[nj] reg r: m = m0 + w*16 + (lane>>4)*4 + r ; n = nj*16 + (lane&15)
// 625 blocks in M (625*64 = 40000 exact, no bounds checks).
// ---------------------------------------------------------------------------

// [so|aw] = Aq @ [WsoT(128)|WawT(64)] single pass, N=192
__global__ __launch_bounds__(256, 4) void gemm_soaw_k(
    const ushort* __restrict__ Aq,
    const ushort* __restrict__ WsoT, const ushort* __restrict__ WawT,
    const float* __restrict__ b_so, const float* __restrict__ b_aw,
    float* __restrict__ so_ws, float* __restrict__ aw_ws) {
  __shared__ __align__(16) char smem[36864];
  ushort (*As)[72] = (ushort(*)[72])smem;                 //  64 x 72
  ushort (*Bs)[72] = (ushort(*)[72])(smem + 9216);        // 192 x 72
  float (*E)[68] = (float(*)[68])smem;                    // epilogue alias
  f32x4 acc[12] = {};
  const int m0 = blockIdx.x * 64;
  const int tid = threadIdx.x;
  uint4 areg[2], breg[6];

  auto load_tiles = [&](int k0) {
#pragma unroll
    for (int i = 0; i < 2; ++i) {
      const int c = tid + i * 256;
      const int row = c >> 3, kc = (c & 7) * 8;
      areg[i] = *(const uint4*)&Aq[(size_t)(m0 + row) * 512 + k0 + kc];
    }
#pragma unroll
    for (int i = 0; i < 6; ++i) {
      const int c = tid + i * 256;
      const int n = c >> 3, kc = (c & 7) * 8;
      const ushort* src = (n < 128) ? &WsoT[(size_t)n * 512 + k0 + kc]
                                    : &WawT[(size_t)(n - 128) * 512 + k0 + kc];
      breg[i] = *(const uint4*)src;
    }
  };

  load_tiles(0);
  const int w = tid >> 6, lane = tid & 63;
  const int rl = lane & 15;
  const int kq = (lane >> 4) * 8;

  for (int k0 = 0; k0 < 512; k0 += 64) {
    __syncthreads();
#pragma unroll
    for (int i = 0; i < 2; ++i) {
      const int c = tid + i * 256;
      *(uint4*)&As[c >> 3][(c & 7) * 8] = areg[i];
    }
#pragma unroll
    for (int i = 0; i < 6; ++i) {
      const int c = tid + i * 256;
      *(uint4*)&Bs[c >> 3][(c & 7) * 8] = breg[i];
    }
    __syncthreads();
    if (k0 + 64 < 512) load_tiles(k0 + 64);
#pragma unroll
    for (int kk = 0; kk < 2; ++kk) {
      short8 af = *(const short8*)&As[w * 16 + rl][kk * 32 + kq];
      short8 bf[12];
#pragma unroll
      for (int nj = 0; nj < 12; ++nj)
        bf[nj] = *(const short8*)&Bs[nj * 16 + rl][kk * 32 + kq];
#pragma unroll
      for (int nj = 0; nj < 12; ++nj)
        acc[nj] = __builtin_amdgcn_mfma_f32_16x16x32_bf16(af, bf[nj], acc[nj], 0, 0, 0);
    }
  }
  __syncthreads();

  const int rbase = (lane >> 4) * 4, cl = lane & 15;
  // passes 0,1: so cols 0-63 / 64-127 ; pass 2: aw (softmax over 4-col groups)
#pragma unroll
  for (int p = 0; p < 3; ++p) {
#pragma unroll
    for (int j = 0; j < 4; ++j) {
      const int nj = p * 4 + j;
      const int nl = j * 16 + cl;
      const f32x4 a = acc[nj];
      if (p < 2) {
        const float bb = b_so[p * 64 + nl];
#pragma unroll
        for (int r = 0; r < 4; ++r)
          E[w * 16 + rbase + r][nl] = a[r] + bb;
      } else {
        const float bb = b_aw[nl];
#pragma unroll
        for (int r = 0; r < 4; ++r) {
          float z = a[r] + bb;
          float zm = fmaxf(z, __shfl_xor(z, 1, 64));
          zm = fmaxf(zm, __shfl_xor(zm, 2, 64));
          float e = expf(z - zm);
          float s = e + __shfl_xor(e, 1, 64);
          s = s + __shfl_xor(s, 2, 64);
          E[w * 16 + rbase + r][nl] = e / s;
        }
      }
    }
    __syncthreads();
#pragma unroll
    for (int it = 0; it < 4; ++it) {
      const int flat = it * 256 + tid;
      const int row = flat >> 4, c4 = (flat & 15) * 4;
      const float4 vle = *(const float4*)&E[row][c4];
      if (p < 2)
        *(float4*)&so_ws[(size_t)(m0 + row) * 128 + p * 64 + c4] = vle;
      else
        *(float4*)&aw_ws[(size_t)(m0 + row) * 64 + c4] = vle;
    }
    __syncthreads();
  }
}

// v = query @ WvT + b_v -> bf16 head-major vt (NH, NQ, 32). N=128/block
__global__ __launch_bounds__(256, 4) void gemm_v_k(
    const ushort* __restrict__ Aq, const ushort* __restrict__ WvT,
    const float* __restrict__ bv, ushort* __restrict__ vt) {
  __shared__ __align__(16) char smem[27648];
  ushort (*As)[72] = (ushort(*)[72])smem;                 //  64 x 72
  ushort (*Bs)[72] = (ushort(*)[72])(smem + 9216);        // 128 x 72
  ushort (*Eb)[72] = (ushort(*)[72])smem;                 // epilogue alias
  f32x4 acc[8] = {};
  const int m0 = blockIdx.x * 64, n0 = blockIdx.y * 128;
  const int tid = threadIdx.x;
  uint4 areg[2], breg[4];

  auto load_tiles = [&](int k0) {
#pragma unroll
    for (int i = 0; i < 2; ++i) {
      const int c = tid + i * 256;
      const int row = c >> 3, kc = (c & 7) * 8;
      areg[i] = *(const uint4*)&Aq[(size_t)(m0 + row) * 512 + k0 + kc];
    }
#pragma unroll
    for (int i = 0; i < 4; ++i) {
      const int c = tid + i * 256;
      const int n = c >> 3, kc = (c & 7) * 8;
      breg[i] = *(const uint4*)&WvT[(size_t)(n0 + n) * 256 + k0 + kc];
    }
  };

  load_tiles(0);
  const int w = tid >> 6, lane = tid & 63;
  const int rl = lane & 15;
  const int kq = (lane >> 4) * 8;

  for (int k0 = 0; k0 < 256; k0 += 64) {
    __syncthreads();
#pragma unroll
    for (int i = 0; i < 2; ++i) {
      const int c = tid + i * 256;
      *(uint4*)&As[c >> 3][(c & 7) * 8] = areg[i];
    }
#pragma unroll
    for (int i = 0; i < 4; ++i) {
      const int c = tid + i * 256;
      *(uint4*)&Bs[c >> 3][(c & 7) * 8] = breg[i];
    }
    __syncthreads();
    if (k0 + 64 < 256) load_tiles(k0 + 64);
#pragma unroll
    for (int kk = 0; kk < 2; ++kk) {
      short8 af = *(const short8*)&As[w * 16 + rl][kk * 32 + kq];
      short8 bf[8];
#pragma unroll
      for (int nj = 0; nj < 8; ++nj)
        bf[nj] = *(const short8*)&Bs[nj * 16 + rl][kk * 32 + kq];
#pragma unroll
      for (int nj = 0; nj < 8; ++nj)
        acc[nj] = __builtin_amdgcn_mfma_f32_16x16x32_bf16(af, bf[nj], acc[nj], 0, 0, 0);
    }
  }
  __syncthreads();

  const int rbase = (lane >> 4) * 4, cl = lane & 15;
#pragma unroll
  for (int p = 0; p < 2; ++p) {  // 64-col halves
#pragma unroll
    for (int j = 0; j < 4; ++j) {
      const int nj = p * 4 + j;
      const int n = n0 + p * 64 + j * 16 + cl;
      const float bb = bv[n];
      const f32x4 a = acc[nj];
#pragma unroll
      for (int r = 0; r < 4; ++r)
        Eb[w * 16 + rbase + r][j * 16 + cl] = f2b(a[r] + bb);
    }
    __syncthreads();
#pragma unroll
    for (int hh = 0; hh < 2; ++hh) {
      const int h = (n0 + p * 64) / 32 + hh;
#pragma unroll
      for (int it = 0; it < 2; ++it) {
        const int flat = it * 256 + tid;
        const int row = flat >> 3, d4 = (flat & 7) * 4;
        *(ushort4*)&vt[((size_t)h * NQc + m0 + row) * 32 + d4] =
            *(const ushort4*)&Eb[row][hh * 32 + d4];
      }
    }
    __syncthreads();
  }
}

// out = out_pre @ WoT + b_o -> fp32 (NQ,256). N=128/block
__global__ __launch_bounds__(256, 4) void gemm_o_k(
    const ushort* __restrict__ Ap, const ushort* __restrict__ WoT,
    const float* __restrict__ bo, float* __restrict__ out) {
  __shared__ __align__(16) char smem[27648];
  ushort (*As)[72] = (ushort(*)[72])smem;
  ushort (*Bs)[72] = (ushort(*)[72])(smem + 9216);
  float (*E)[68] = (float(*)[68])smem;
  f32x4 acc[8] = {};
  const int m0 = blockIdx.x * 64, n0 = blockIdx.y * 128;
  const int tid = threadIdx.x;
  uint4 areg[2], breg[4];

  auto load_tiles = [&](int k0) {
#pragma unroll
    for (int i = 0; i < 2; ++i) {
      const int c = tid + i * 256;
      const int row = c >> 3, kc = (c & 7) * 8;
      areg[i] = *(const uint4*)&Ap[(size_t)(m0 + row) * 256 + k0 + kc];
    }
#pragma unroll
    for (int i = 0; i < 4; ++i) {
      const int c = tid + i * 256;
      const int n = c >> 3, kc = (c & 7) * 8;
      breg[i] = *(const uint4*)&WoT[(size_t)(n0 + n) * 256 + k0 + kc];
    }
  };

  load_tiles(0);
  const int w = tid >> 6, lane = tid & 63;
  const int rl = lane & 15;
  const int kq = (lane >> 4) * 8;

  for (int k0 = 0; k0 < 256; k0 += 64) {
    __syncthreads();
#pragma unroll
    for (int i = 0; i < 2; ++i) {
      const int c = tid + i * 256;
      *(uint4*)&As[c >> 3][(c & 7) * 8] = areg[i];
    }
#pragma unroll
    for (int i = 0; i < 4; ++i) {
      const int c = tid + i * 256;
      *(uint4*)&Bs[c >> 3][(c & 7) * 8] = breg[i];
    }
    __syncthreads();
    if (k0 + 64 < 256) load_tiles(k0 + 64);
#pragma unroll
    for (int kk = 0; kk < 2; ++kk) {
      short8 af = *(const short8*)&As[w * 16 + rl][kk * 32 + kq];
      short8 bf[8];
#pragma unroll
      for (int nj = 0; nj < 8; ++nj)
        bf[nj] = *(const short8*)&Bs[nj * 16 + rl][kk * 32 + kq];
#pragma unroll
      for (int nj = 0; nj < 8; ++nj)
        acc[nj] = __builtin_amdgcn_mfma_f32_16x16x32_bf16(af, bf[nj], acc[nj], 0, 0, 0);
    }
  }
  __syncthreads();

  const int rbase = (lane >> 4) * 4, cl = lane & 15;
#pragma unroll
  for (int p = 0; p < 2; ++p) {
#pragma unroll
    for (int j = 0; j < 4; ++j) {
      const int nj = p * 4 + j;
      const int n = n0 + p * 64 + j * 16 + cl;
      const float bb = bo[n];
      const f32x4 a = acc[nj];
#pragma unroll
      for (int r = 0; r < 4; ++r)
        E[w * 16 + rbase + r][j * 16 + cl] = a[r] + bb;
    }
    __syncthreads();
#pragma unroll
    for (int it = 0; it < 4; ++it) {
      const int flat = it * 256 + tid;
      const int row = flat >> 4, c4 = (flat & 15) * 4;
      *(float4*)&out[(size_t)(m0 + row) * 256 + n0 + p * 64 + c4] =
          *(const float4*)&E[row][c4];
    }
    __syncthreads();
  }
}

// ---------------------------------------------------------------------------
// Deformable sampling: block = one head x 32 queries; head = blockIdx.x & 7
// pins each head's 2.56 MB vt slice to one XCD's L2.
// ---------------------------------------------------------------------------
__global__ __launch_bounds__(256) void sample_kernel(
    const ushort* __restrict__ vt,    // (NH, NQ, 32) bf16
    const float* __restrict__ so_ws,  // (NQ, 128)
    const float* __restrict__ aw_ws,  // (NQ, 64)
    const float* __restrict__ refp,   // (NQ, 2)
    ushort* __restrict__ out_pre)     // (NQ, 256) bf16
{
  __shared__ int   offs[8][32][4];
  __shared__ float wts [8][32][4];
  const int h  = blockIdx.x & 7;
  const int m0 = (blockIdx.x >> 3) * 32;
  const int tid = threadIdx.x;

  {
    const int j  = tid & 7;          // q*4 + p
    const int qi = tid >> 3;
    const int m  = m0 + qi;
    const int c  = h * 8 + j;
    const float sx  = so_ws[(size_t)m * 128 + c * 2 + 0];
    const float sy  = so_ws[(size_t)m * 128 + c * 2 + 1];
    const float wgt = aw_ws[(size_t)m * 64 + c];
    const float x = refp[m * 2 + 0] * (float)Wc + sx - 0.5f;
    const float y = refp[m * 2 + 1] * (float)Hc + sy - 0.5f;
    const float x0f = floorf(x), y0f = floorf(y);
    const int x0 = (int)x0f, y0 = (int)y0f;
    const int x1 = x0 + 1, y1 = y0 + 1;
    const float wx1 = x - x0f, wx0 = 1.0f - wx1;
    const float wy1 = y - y0f, wy0 = 1.0f - wy1;
    const bool vx0 = (x0 >= 0) & (x0 < Wc), vx1 = (x1 >= 0) & (x1 < Wc);
    const bool vy0 = (y0 >= 0) & (y0 < Hc), vy1 = (y1 >= 0) & (y1 < Hc);
    const int cx0 = min(max(x0, 0), Wc - 1), cx1 = min(max(x1, 0), Wc - 1);
    const int cy0 = min(max(y0, 0), Hc - 1), cy1 = min(max(y1, 0), Hc - 1);
    offs[j][qi][0] = (cy0 * Wc + cx0) * 32;
    offs[j][qi][1] = (cy0 * Wc + cx1) * 32;
    offs[j][qi][2] = (cy1 * Wc + cx0) * 32;
    offs[j][qi][3] = (cy1 * Wc + cx1) * 32;
    wts[j][qi][0] = (vx0 & vy0) ? wgt * wx0 * wy0 : 0.0f;
    wts[j][qi][1] = (vx1 & vy0) ? wgt * wx1 * wy0 : 0.0f;
    wts[j][qi][2] = (vx0 & vy1) ? wgt * wx0 * wy1 : 0.0f;
    wts[j][qi][3] = (vx1 & vy1) ? wgt * wx1 * wy1 : 0.0f;
  }
  __syncthreads();

  const int qi = tid >> 3;
  const int ld = tid & 7;
  const int m  = m0 + qi;
  const ushort* __restrict__ vh = vt + (size_t)h * NQc * 32 + ld * 4;
  float a0 = 0.f, a1 = 0.f, a2 = 0.f, a3 = 0.f;
#pragma unroll
  for (int j = 0; j < 8; ++j) {
    const int4   o = *(const int4*)&offs[j][qi][0];
    const float4 w = *(const float4*)&wts[j][qi][0];
#pragma unroll
    for (int k = 0; k < 4; ++k) {
      const int oo = (k == 0) ? o.x : (k == 1) ? o.y : (k == 2) ? o.z : o.w;
      const float ww = (k == 0) ? w.x : (k == 1) ? w.y : (k == 2) ? w.z : w.w;
      const uint2 raw = *(const uint2*)&vh[oo];
      const float f0 = __uint_as_float(raw.x << 16);
      const float f1 = __uint_as_float(raw.x & 0xFFFF0000u);
      const float f2 = __uint_as_float(raw.y << 16);
      const float f3 = __uint_as_float(raw.y & 0xFFFF0000u);
      a0 = fmaf(ww, f0, a0);
      a1 = fmaf(ww, f1, a1);
      a2 = fmaf(ww, f2, a2);
      a3 = fmaf(ww, f3, a3);
    }
  }
  ushort4 o = { f2b(0.5f * a0), f2b(0.5f * a1), f2b(0.5f * a2), f2b(0.5f * a3) };
  *(ushort4*)&out_pre[(size_t)m * 256 + h * 32 + ld * 4] = o;
}

extern "C" void kernel_launch(void* const* d_in, const int* in_sizes, int n_in,
                              void* d_out, int out_size, void* d_ws, size_t ws_size,
                              hipStream_t stream) {
  const float* query     = (const float*)d_in[0];
  const float* query_pos = (const float*)d_in[1];
  const float* refp      = (const float*)d_in[2];
  const float* W_so      = (const float*)d_in[3];
  const float* b_so      = (const float*)d_in[4];
  const float* W_aw      = (const float*)d_in[5];
  const float* b_aw      = (const float*)d_in[6];
  const float* W_v       = (const float*)d_in[7];
  const float* b_v       = (const float*)d_in[8];
  const float* W_o       = (const float*)d_in[9];
  const float* b_o       = (const float*)d_in[10];
  float* out = (float*)d_out;

  // workspace layout (bytes), total ~92.6 MB
  char* base = (char*)d_ws;
  ushort* Aq      = (ushort*)base;                       // 40,960,000 B
  ushort* out_pre = (ushort*)base;                       // aliases Aq (dead)
  ushort* vt      = (ushort*)(base + 40960000);          // 20,480,000 B
  float*  so_ws   = (float*)(base + 61440000);           // 20,480,000 B
  float*  aw_ws   = (float*)(base + 81920000);           // 10,240,000 B
  ushort* WvT     = (ushort*)(base + 92160000);
  ushort* WoT     = WvT + 65536;
  ushort* WsoT    = WoT + 65536;
  ushort* WawT    = WsoT + 65536;

  prep_all<<<10896, 256, 0, stream>>>(query, query_pos, W_v, W_o, W_so, W_aw,
                                      Aq, WvT, WoT, WsoT, WawT);
  gemm_v_k<<<dim3(625, 2), 256, 0, stream>>>(Aq, WvT, b_v, vt);
  gemm_soaw_k<<<625, 256, 0, stream>>>(Aq, WsoT, WawT, b_so, b_aw, so_ws, aw_ws);
  sample_kernel<<<10000, 256, 0, stream>>>(vt, so_ws, aw_ws, refp, out_pre);
  gemm_o_k<<<dim3(625, 2), 256, 0, stream>>>(out_pre, WoT, b_o, out);
}

// Round 6
// 237.727 us; speedup vs baseline: 1.4449x; 1.4449x over previous
//
#include <hip/hip_runtime.h>
#include <math.h>

#define NQc 40000
#define Wc 200
#define Hc 200

typedef __attribute__((ext_vector_type(8))) short short8;
typedef __attribute__((ext_vector_type(4))) float f32x4;

__device__ __forceinline__ ushort f2b(float f) {
  unsigned u = __float_as_uint(f);
  u = (u + 0x7fffu + ((u >> 16) & 1u)) >> 16;
  return (ushort)u;
}

// async global->LDS, 16B per lane; LDS dest must be base + lane*16 contiguous
__device__ __forceinline__ void glds16(const void* g, void* l) {
  __builtin_amdgcn_global_load_lds(
      (const __attribute__((address_space(1))) void*)g,
      (__attribute__((address_space(3))) void*)l, 16, 0, 0);
}

// ---------------------------------------------------------------------------
// weights -> bf16, transposed to (N, K)
// ---------------------------------------------------------------------------
__global__ __launch_bounds__(256) void prep_w(
    const float* __restrict__ Wv, const float* __restrict__ Wo,
    const float* __restrict__ Wso, const float* __restrict__ Waw,
    ushort* __restrict__ WvT, ushort* __restrict__ WoT,
    ushort* __restrict__ WsoT, ushort* __restrict__ WawT) {
  const int idx = blockIdx.x * 256 + threadIdx.x;
  if (idx < 65536) {
    int n = idx >> 8, k = idx & 255;
    WvT[idx] = f2b(Wv[k * 256 + n]);
  } else if (idx < 131072) {
    int i = idx - 65536;
    int n = i >> 8, k = i & 255;
    WoT[i] = f2b(Wo[k * 256 + n]);
  } else if (idx < 196608) {
    int i = idx - 131072;
    int n = i >> 9, k = i & 511;
    WsoT[i] = f2b(Wso[k * 128 + n]);
  } else {
    int i = idx - 196608;
    int n = i >> 9, k = i & 511;
    WawT[i] = f2b(Waw[k * 64 + n]);
  }
}

// ---------------------------------------------------------------------------
// Swizzle convention for unpadded LDS tiles (64 ushorts = 8 chunks of 16B/row):
// LDS slot (row, c) holds global 16B-chunk (c ^ (row & 7)). glds writes are
// lane-contiguous (base + lane*16); ds_read_b128 spreads banks 2-way max.
// ---------------------------------------------------------------------------

// [so|aw] = [q | q+qp] @ [WsoT(128)|WawT(64)]^T, N=192, K=512, BM=64.
// A staged via fp32 load + in-reg bf16 cvt (padded As); B via async glds.
__global__ __launch_bounds__(256, 3) void gemm_soaw_k(
    const float* __restrict__ q, const float* __restrict__ qp,
    const ushort* __restrict__ WsoT, const ushort* __restrict__ WawT,
    const float* __restrict__ b_so, const float* __restrict__ b_aw,
    float* __restrict__ so_ws, float* __restrict__ aw_ws) {
  __shared__ __align__(16) char smem[33792];
  ushort (*As)[72] = (ushort(*)[72])smem;     // 64 x 72 padded (9216 B)
  ushort* BsU = (ushort*)(smem + 9216);       // 192 x 64 swizzled (24576 B)
  float (*E)[68] = (float(*)[68])smem;        // epilogue alias (17408 B)
  f32x4 acc[12] = {};
  const int m0 = blockIdx.x * 64;
  const int tid = threadIdx.x;
  const int w = tid >> 6, lane = tid & 63;
  const int rl = lane & 15, q2 = lane >> 4;
  const int sw8 = rl & 7;
  const int lrow = lane >> 3, lch = (lane & 7) ^ (lrow & 7);
  const int arow = tid >> 2, ac16 = (tid & 3) * 16;
  const float* qrow  = q  + (size_t)(m0 + arow) * 256 + ac16;
  const float* qprow = qp + (size_t)(m0 + arow) * 256 + ac16;

  float4 f[4], g4[4];
#pragma unroll
  for (int i = 0; i < 4; ++i) f[i] = *(const float4*)(qrow + i * 4);

  for (int k0 = 0; k0 < 512; k0 += 64) {
    const bool hi = (k0 >= 256);
    __syncthreads();
    // B: 192 rows, 24 groups of 8, 6 per wave, async to LDS
#pragma unroll
    for (int i = 0; i < 6; ++i) {
      const int g = w * 6 + i;
      const int row = g * 8 + lrow;
      const ushort* gsrc = (row < 128)
          ? WsoT + (size_t)row * 512 + k0 + lch * 8
          : WawT + (size_t)(row - 128) * 512 + k0 + lch * 8;
      glds16(gsrc, BsU + g * 512 + lane * 8);
    }
    // A: cvt prefetched fp32 -> bf16 -> LDS
    {
      ushort tmp[16];
#pragma unroll
      for (int i = 0; i < 4; ++i) {
        float4 a = f[i];
        if (hi) { float4 b = g4[i]; a.x += b.x; a.y += b.y; a.z += b.z; a.w += b.w; }
        tmp[i * 4 + 0] = f2b(a.x); tmp[i * 4 + 1] = f2b(a.y);
        tmp[i * 4 + 2] = f2b(a.z); tmp[i * 4 + 3] = f2b(a.w);
      }
      *(uint4*)&As[arow][ac16]     = *(const uint4*)&tmp[0];
      *(uint4*)&As[arow][ac16 + 8] = *(const uint4*)&tmp[8];
    }
    __syncthreads();
    if (k0 + 64 < 512) {
      const int kn = k0 + 64;
      const int kq = (kn >= 256) ? kn - 256 : kn;
#pragma unroll
      for (int i = 0; i < 4; ++i) f[i] = *(const float4*)(qrow + kq + i * 4);
      if (kn >= 256) {
#pragma unroll
        for (int i = 0; i < 4; ++i) g4[i] = *(const float4*)(qprow + kq + i * 4);
      }
    }
#pragma unroll
    for (int kk = 0; kk < 2; ++kk) {
      const short8 af = *(const short8*)&As[w * 16 + rl][kk * 32 + q2 * 8];
#pragma unroll
      for (int nj = 0; nj < 12; ++nj) {
        const short8 bf = *(const short8*)
            &BsU[(nj * 16 + rl) * 64 + ((kk * 4 + q2) ^ sw8) * 8];
        acc[nj] = __builtin_amdgcn_mfma_f32_16x16x32_bf16(af, bf, acc[nj], 0, 0, 0);
      }
    }
  }
  __syncthreads();

  const int rbase = q2 * 4, cl = rl;
#pragma unroll
  for (int p = 0; p < 3; ++p) {
#pragma unroll
    for (int j = 0; j < 4; ++j) {
      const int nj = p * 4 + j;
      const int nl = j * 16 + cl;
      const f32x4 a = acc[nj];
      if (p < 2) {
        const float bb = b_so[p * 64 + nl];
#pragma unroll
        for (int r = 0; r < 4; ++r)
          E[w * 16 + rbase + r][nl] = a[r] + bb;
      } else {
        const float bb = b_aw[nl];
#pragma unroll
        for (int r = 0; r < 4; ++r) {
          float z = a[r] + bb;
          float zm = fmaxf(z, __shfl_xor(z, 1, 64));
          zm = fmaxf(zm, __shfl_xor(zm, 2, 64));
          float e = expf(z - zm);
          float s = e + __shfl_xor(e, 1, 64);
          s = s + __shfl_xor(s, 2, 64);
          E[w * 16 + rbase + r][nl] = e / s;
        }
      }
    }
    __syncthreads();
#pragma unroll
    for (int it = 0; it < 4; ++it) {
      const int flat = it * 256 + tid;
      const int row = flat >> 4, c4 = (flat & 15) * 4;
      const float4 vle = *(const float4*)&E[row][c4];
      if (p < 2)
        *(float4*)&so_ws[(size_t)(m0 + row) * 128 + p * 64 + c4] = vle;
      else
        *(float4*)&aw_ws[(size_t)(m0 + row) * 64 + c4] = vle;
    }
    __syncthreads();
  }
}

// v = q @ WvT + b_v -> bf16 head-major vt (NH, NQ, 32). N=128/block, K=256.
__global__ __launch_bounds__(256, 3) void gemm_v_k(
    const float* __restrict__ q, const ushort* __restrict__ WvT,
    const float* __restrict__ bv, ushort* __restrict__ vt) {
  __shared__ __align__(16) char smem[25600];
  ushort (*As)[72] = (ushort(*)[72])smem;     // 64 x 72 padded
  ushort* BsU = (ushort*)(smem + 9216);       // 128 x 64 swizzled (16384 B)
  ushort (*Eb)[72] = (ushort(*)[72])smem;     // epilogue alias
  f32x4 acc[8] = {};
  const int m0 = blockIdx.x * 64, n0 = blockIdx.y * 128;
  const int tid = threadIdx.x;
  const int w = tid >> 6, lane = tid & 63;
  const int rl = lane & 15, q2 = lane >> 4;
  const int sw8 = rl & 7;
  const int lrow = lane >> 3, lch = (lane & 7) ^ (lrow & 7);
  const int arow = tid >> 2, ac16 = (tid & 3) * 16;
  const float* qrow = q + (size_t)(m0 + arow) * 256 + ac16;

  float4 f[4];
#pragma unroll
  for (int i = 0; i < 4; ++i) f[i] = *(const float4*)(qrow + i * 4);

  for (int k0 = 0; k0 < 256; k0 += 64) {
    __syncthreads();
#pragma unroll
    for (int i = 0; i < 4; ++i) {
      const int g = w * 4 + i;
      const int row = g * 8 + lrow;
      glds16(WvT + (size_t)(n0 + row) * 256 + k0 + lch * 8,
             BsU + g * 512 + lane * 8);
    }
    {
      ushort tmp[16];
#pragma unroll
      for (int i = 0; i < 4; ++i) {
        const float4 a = f[i];
        tmp[i * 4 + 0] = f2b(a.x); tmp[i * 4 + 1] = f2b(a.y);
        tmp[i * 4 + 2] = f2b(a.z); tmp[i * 4 + 3] = f2b(a.w);
      }
      *(uint4*)&As[arow][ac16]     = *(const uint4*)&tmp[0];
      *(uint4*)&As[arow][ac16 + 8] = *(const uint4*)&tmp[8];
    }
    __syncthreads();
    if (k0 + 64 < 256) {
#pragma unroll
      for (int i = 0; i < 4; ++i) f[i] = *(const float4*)(qrow + k0 + 64 + i * 4);
    }
#pragma unroll
    for (int kk = 0; kk < 2; ++kk) {
      const short8 af = *(const short8*)&As[w * 16 + rl][kk * 32 + q2 * 8];
#pragma unroll
      for (int nj = 0; nj < 8; ++nj) {
        const short8 bf = *(const short8*)
            &BsU[(nj * 16 + rl) * 64 + ((kk * 4 + q2) ^ sw8) * 8];
        acc[nj] = __builtin_amdgcn_mfma_f32_16x16x32_bf16(af, bf, acc[nj], 0, 0, 0);
      }
    }
  }
  __syncthreads();

  const int rbase = q2 * 4, cl = rl;
#pragma unroll
  for (int p = 0; p < 2; ++p) {
#pragma unroll
    for (int j = 0; j < 4; ++j) {
      const int nj = p * 4 + j;
      const int n = n0 + p * 64 + j * 16 + cl;
      const float bb = bv[n];
      const f32x4 a = acc[nj];
#pragma unroll
      for (int r = 0; r < 4; ++r)
        Eb[w * 16 + rbase + r][j * 16 + cl] = f2b(a[r] + bb);
    }
    __syncthreads();
#pragma unroll
    for (int hh = 0; hh < 2; ++hh) {
      const int h = (n0 + p * 64) / 32 + hh;
#pragma unroll
      for (int it = 0; it < 2; ++it) {
        const int flat = it * 256 + tid;
        const int row = flat >> 3, d4 = (flat & 7) * 4;
        *(ushort4*)&vt[((size_t)h * NQc + m0 + row) * 32 + d4] =
            *(const ushort4*)&Eb[row][hh * 32 + d4];
      }
    }
    __syncthreads();
  }
}

// out = out_pre @ WoT + b_o -> fp32. N=128/block, K=256. Fully async A+B.
__global__ __launch_bounds__(256, 4) void gemm_o_k(
    const ushort* __restrict__ Ap, const ushort* __restrict__ WoT,
    const float* __restrict__ bo, float* __restrict__ out) {
  __shared__ __align__(16) char smem[24576];
  ushort* AsU = (ushort*)smem;                // 64 x 64 swizzled (8192 B)
  ushort* BsU = (ushort*)(smem + 8192);       // 128 x 64 swizzled (16384 B)
  float (*E)[68] = (float(*)[68])smem;        // epilogue alias (17408 B)
  f32x4 acc[8] = {};
  const int m0 = blockIdx.x * 64, n0 = blockIdx.y * 128;
  const int tid = threadIdx.x;
  const int w = tid >> 6, lane = tid & 63;
  const int rl = lane & 15, q2 = lane >> 4;
  const int sw8 = rl & 7;
  const int lrow = lane >> 3, lch = (lane & 7) ^ (lrow & 7);

  for (int k0 = 0; k0 < 256; k0 += 64) {
    __syncthreads();
#pragma unroll
    for (int i = 0; i < 2; ++i) {
      const int g = w * 2 + i;
      const int row = g * 8 + lrow;
      glds16(Ap + (size_t)(m0 + row) * 256 + k0 + lch * 8,
             AsU + g * 512 + lane * 8);
    }
#pragma unroll
    for (int i = 0; i < 4; ++i) {
      const int g = w * 4 + i;
      const int row = g * 8 + lrow;
      glds16(WoT + (size_t)(n0 + row) * 256 + k0 + lch * 8,
             BsU + g * 512 + lane * 8);
    }
    __syncthreads();
#pragma unroll
    for (int kk = 0; kk < 2; ++kk) {
      const short8 af = *(const short8*)
          &AsU[(w * 16 + rl) * 64 + ((kk * 4 + q2) ^ sw8) * 8];
#pragma unroll
      for (int nj = 0; nj < 8; ++nj) {
        const short8 bf = *(const short8*)
            &BsU[(nj * 16 + rl) * 64 + ((kk * 4 + q2) ^ sw8) * 8];
        acc[nj] = __builtin_amdgcn_mfma_f32_16x16x32_bf16(af, bf, acc[nj], 0, 0, 0);
      }
    }
  }
  __syncthreads();

  const int rbase = q2 * 4, cl = rl;
#pragma unroll
  for (int p = 0; p < 2; ++p) {
#pragma unroll
    for (int j = 0; j < 4; ++j) {
      const int nj = p * 4 + j;
      const int n = n0 + p * 64 + j * 16 + cl;
      const float bb = bo[n];
      const f32x4 a = acc[nj];
#pragma unroll
      for (int r = 0; r < 4; ++r)
        E[w * 16 + rbase + r][j * 16 + cl] = a[r] + bb;
    }
    __syncthreads();
#pragma unroll
    for (int it = 0; it < 4; ++it) {
      const int flat = it * 256 + tid;
      const int row = flat >> 4, c4 = (flat & 15) * 4;
      *(float4*)&out[(size_t)(m0 + row) * 256 + n0 + p * 64 + c4] =
          *(const float4*)&E[row][c4];
    }
    __syncthreads();
  }
}

// ---------------------------------------------------------------------------
// Deformable sampling: block = one head x 32 queries; head = blockIdx.x & 7
// pins each head's 2.56 MB vt slice to one XCD's L2.
// ---------------------------------------------------------------------------
__global__ __launch_bounds__(256) void sample_kernel(
    const ushort* __restrict__ vt,    // (NH, NQ, 32) bf16
    const float* __restrict__ so_ws,  // (NQ, 128)
    const float* __restrict__ aw_ws,  // (NQ, 64)
    const float* __restrict__ refp,   // (NQ, 2)
    ushort* __restrict__ out_pre)     // (NQ, 256) bf16
{
  __shared__ int   offs[8][32][4];
  __shared__ float wts [8][32][4];
  const int h  = blockIdx.x & 7;
  const int m0 = (blockIdx.x >> 3) * 32;
  const int tid = threadIdx.x;

  {
    const int j  = tid & 7;          // q*4 + p
    const int qi = tid >> 3;
    const int m  = m0 + qi;
    const int c  = h * 8 + j;
    const float sx  = so_ws[(size_t)m * 128 + c * 2 + 0];
    const float sy  = so_ws[(size_t)m * 128 + c * 2 + 1];
    const float wgt = aw_ws[(size_t)m * 64 + c];
    const float x = refp[m * 2 + 0] * (float)Wc + sx - 0.5f;
    const float y = refp[m * 2 + 1] * (float)Hc + sy - 0.5f;
    const float x0f = floorf(x), y0f = floorf(y);
    const int x0 = (int)x0f, y0 = (int)y0f;
    const int x1 = x0 + 1, y1 = y0 + 1;
    const float wx1 = x - x0f, wx0 = 1.0f - wx1;
    const float wy1 = y - y0f, wy0 = 1.0f - wy1;
    const bool vx0 = (x0 >= 0) & (x0 < Wc), vx1 = (x1 >= 0) & (x1 < Wc);
    const bool vy0 = (y0 >= 0) & (y0 < Hc), vy1 = (y1 >= 0) & (y1 < Hc);
    const int cx0 = min(max(x0, 0), Wc - 1), cx1 = min(max(x1, 0), Wc - 1);
    const int cy0 = min(max(y0, 0), Hc - 1), cy1 = min(max(y1, 0), Hc - 1);
    offs[j][qi][0] = (cy0 * Wc + cx0) * 32;
    offs[j][qi][1] = (cy0 * Wc + cx1) * 32;
    offs[j][qi][2] = (cy1 * Wc + cx0) * 32;
    offs[j][qi][3] = (cy1 * Wc + cx1) * 32;
    wts[j][qi][0] = (vx0 & vy0) ? wgt * wx0 * wy0 : 0.0f;
    wts[j][qi][1] = (vx1 & vy0) ? wgt * wx1 * wy0 : 0.0f;
    wts[j][qi][2] = (vx0 & vy1) ? wgt * wx0 * wy1 : 0.0f;
    wts[j][qi][3] = (vx1 & vy1) ? wgt * wx1 * wy1 : 0.0f;
  }
  __syncthreads();

  const int qi = tid >> 3;
  const int ld = tid & 7;
  const int m  = m0 + qi;
  const ushort* __restrict__ vh = vt + (size_t)h * NQc * 32 + ld * 4;
  float a0 = 0.f, a1 = 0.f, a2 = 0.f, a3 = 0.f;
#pragma unroll
  for (int j = 0; j < 8; ++j) {
    const int4   o = *(const int4*)&offs[j][qi][0];
    const float4 w = *(const float4*)&wts[j][qi][0];
#pragma unroll
    for (int k = 0; k < 4; ++k) {
      const int oo = (k == 0) ? o.x : (k == 1) ? o.y : (k == 2) ? o.z : o.w;
      const float ww = (k == 0) ? w.x : (k == 1) ? w.y : (k == 2) ? w.z : w.w;
      const uint2 raw = *(const uint2*)&vh[oo];
      const float f0 = __uint_as_float(raw.x << 16);
      const float f1 = __uint_as_float(raw.x & 0xFFFF0000u);
      const float f2 = __uint_as_float(raw.y << 16);
      const float f3 = __uint_as_float(raw.y & 0xFFFF0000u);
      a0 = fmaf(ww, f0, a0);
      a1 = fmaf(ww, f1, a1);
      a2 = fmaf(ww, f2, a2);
      a3 = fmaf(ww, f3, a3);
    }
  }
  ushort4 o = { f2b(0.5f * a0), f2b(0.5f * a1), f2b(0.5f * a2), f2b(0.5f * a3) };
  *(ushort4*)&out_pre[(size_t)m * 256 + h * 32 + ld * 4] = o;
}

extern "C" void kernel_launch(void* const* d_in, const int* in_sizes, int n_in,
                              void* d_out, int out_size, void* d_ws, size_t ws_size,
                              hipStream_t stream) {
  const float* query     = (const float*)d_in[0];
  const float* query_pos = (const float*)d_in[1];
  const float* refp      = (const float*)d_in[2];
  const float* W_so      = (const float*)d_in[3];
  const float* b_so      = (const float*)d_in[4];
  const float* W_aw      = (const float*)d_in[5];
  const float* b_aw      = (const float*)d_in[6];
  const float* W_v       = (const float*)d_in[7];
  const float* b_v       = (const float*)d_in[8];
  const float* W_o       = (const float*)d_in[9];
  const float* b_o       = (const float*)d_in[10];
  float* out = (float*)d_out;

  // workspace layout (bytes), total ~72.1 MB (no Aq buffer anymore)
  char* base = (char*)d_ws;
  ushort* vt      = (ushort*)base;                       // 20,480,000 B
  float*  so_ws   = (float*)(base + 20480000);           // 20,480,000 B
  float*  aw_ws   = (float*)(base + 40960000);           // 10,240,000 B
  ushort* out_pre = (ushort*)(base + 51200000);          // 20,480,000 B
  ushort* WvT     = (ushort*)(base + 71680000);          // 131,072 B
  ushort* WoT     = WvT + 65536;                         // 131,072 B
  ushort* WsoT    = WoT + 65536;                         // 131,072 B
  ushort* WawT    = WsoT + 65536;                        //  65,536 B

  prep_w<<<896, 256, 0, stream>>>(W_v, W_o, W_so, W_aw, WvT, WoT, WsoT, WawT);
  gemm_v_k<<<dim3(625, 2), 256, 0, stream>>>(query, WvT, b_v, vt);
  gemm_soaw_k<<<625, 256, 0, stream>>>(query, query_pos, WsoT, WawT,
                                       b_so, b_aw, so_ws, aw_ws);
  sample_kernel<<<10000, 256, 0, stream>>>(vt, so_ws, aw_ws, refp, out_pre);
  gemm_o_k<<<dim3(625, 2), 256, 0, stream>>>(out_pre, WoT, b_o, out);
}